// Round 8
// baseline (343.964 us; speedup 1.0000x reference)
//
#include <hip/hip_runtime.h>
#include <stdint.h>

#define B 8
#define N 200000
#define C 80
#define K 2000
#define HBUCK 4096
#define CAND_CAP 2048
#define BOUND_CAP 2048
#define ENT_M 4096              // CAND_CAP + BOUND_CAP
#define RANK_BLKS 16            // ENT_M / 256
#define BLK 256
#define CHUNK_ROWS 256
#define NCHUNK ((N + CHUNK_ROWS - 1) / CHUNK_ROWS)    // 782 chunks per batch
#define F4_PER_ROW (C / 4)                            // 20
#define ROW_STRIDE 21                                 // coprime 32 -> conflict-free
#define F4_PER_THREAD (CHUNK_ROWS * F4_PER_ROW / BLK) // 20
#define BPB4 ((N + 1023) / 1024)                      // 196 blocks per batch (uint4)

// Bucket mapping: scores are float bits in (0, 1.0); off = 0x3F800000 - bits >= 1.
// bucket = min(4095, (off-1)>>8): buckets 0..4094 are 256-ulp slices of (0.9375, 1),
// bucket 4095 holds everything below. Descending score == ascending bucket.
__device__ __forceinline__ uint32_t key_bucket(uint32_t key) {
    uint32_t off = 0x3F800000u - key;
    uint32_t b = (off - 1u) >> 8;
    return b > 4095u ? 4095u : b;
}

// ---------------- kernel 0: init outputs(-1), hist(0), state(0) ----------
__global__ void k_init(float* out, uint32_t* hist, uint32_t* state) {
    int i = blockIdx.x * blockDim.x + threadIdx.x;
    if (i < B * K * 8) out[i] = -1.0f;
    if (i < B * HBUCK) hist[i] = 0;
    if (i < B * 8) state[i] = 0;
}

// ---------------- kernel 1: PURE STREAM: score + argmax -> keys/labels ---
// No hist, no atomics, no flush. One chunk of 256 rows per block.
__global__ __launch_bounds__(BLK) void k_stream(const float* __restrict__ cls,
                                                uint32_t* __restrict__ keys,
                                                uint8_t* __restrict__ labels) {
    __shared__ float    sval[CHUNK_ROWS * ROW_STRIDE];      // 21 KB
    __shared__ uint16_t sidx[CHUNK_ROWS * ROW_STRIDE];      // 10.5 KB
    int b = blockIdx.x / NCHUNK;
    int row0 = (blockIdx.x % NCHUNK) * CHUNK_ROWS;
    const float4* src = (const float4*)(cls + ((size_t)b * N + row0) * C);

    if (row0 + CHUNK_ROWS <= N) {
        float4 v[F4_PER_THREAD];
        #pragma unroll
        for (int kk = 0; kk < F4_PER_THREAD; ++kk)
            v[kk] = src[threadIdx.x + kk * BLK];
        #pragma unroll
        for (int kk = 0; kk < F4_PER_THREAD; ++kk) {
            int f = threadIdx.x + kk * BLK;
            int r = f / F4_PER_ROW;
            int cc = f % F4_PER_ROW;
            float m4 = v[kk].x; uint32_t a4 = 0;
            if (v[kk].y > m4) { m4 = v[kk].y; a4 = 1; }
            if (v[kk].z > m4) { m4 = v[kk].z; a4 = 2; }
            if (v[kk].w > m4) { m4 = v[kk].w; a4 = 3; }
            sval[r * ROW_STRIDE + cc] = m4;
            sidx[r * ROW_STRIDE + cc] = (uint16_t)(cc * 4 + a4);
        }
    } else {
        #pragma unroll
        for (int kk = 0; kk < F4_PER_THREAD; ++kk) {
            int f = threadIdx.x + kk * BLK;
            int r = f / F4_PER_ROW;
            int cc = f % F4_PER_ROW;
            float m4 = -1.0f; uint32_t a4 = 0;
            if (row0 + r < N) {
                float4 v = src[f];
                m4 = v.x; a4 = 0;
                if (v.y > m4) { m4 = v.y; a4 = 1; }
                if (v.z > m4) { m4 = v.z; a4 = 2; }
                if (v.w > m4) { m4 = v.w; a4 = 3; }
            }
            sval[r * ROW_STRIDE + cc] = m4;
            sidx[r * ROW_STRIDE + cc] = (uint16_t)(cc * 4 + a4);
        }
    }
    __syncthreads();

    int grow = row0 + threadIdx.x;
    if (grow < N) {
        int base = threadIdx.x * ROW_STRIDE;
        float maxv = -1.0f; uint32_t maxi = 0;
        #pragma unroll
        for (int cc = 0; cc < F4_PER_ROW; ++cc) {
            float v = sval[base + cc];
            if (v > maxv) { maxv = v; maxi = sidx[base + cc]; }
        }
        uint32_t key = (maxv > 0.05f) ? __float_as_uint(maxv) : 0u;
        keys[(size_t)b * N + grow] = key;
        labels[(size_t)b * N + grow] = (uint8_t)maxi;
    }
}

// ---------------- kernel 1b: hist from keys (LDS + spread global flush) --
__global__ __launch_bounds__(BLK) void k_hist(const uint32_t* __restrict__ keys,
                                              uint32_t* __restrict__ hist) {
    __shared__ uint32_t h[HBUCK];
    for (int t = threadIdx.x; t < HBUCK; t += BLK) h[t] = 0;
    __syncthreads();
    int b = blockIdx.x / BPB4;
    int base = (blockIdx.x % BPB4) * 1024 + threadIdx.x * 4;
    if (base < N) {
        uint4 kv = *(const uint4*)(keys + (size_t)b * N + base);
        if (kv.x) atomicAdd(&h[key_bucket(kv.x)], 1u);
        if (kv.y) atomicAdd(&h[key_bucket(kv.y)], 1u);
        if (kv.z) atomicAdd(&h[key_bucket(kv.z)], 1u);
        if (kv.w) atomicAdd(&h[key_bucket(kv.w)], 1u);
    }
    __syncthreads();
    for (int t = threadIdx.x; t < HBUCK; t += BLK) {
        uint32_t c = h[t];
        if (c) atomicAdd(&hist[b * HBUCK + t], c);
    }
}

// ---------------- kernel 2: per-batch prefix scan -> cutoff bucket -------
__global__ __launch_bounds__(256) void k_scan(const uint32_t* __restrict__ hist,
                                              uint32_t* __restrict__ state) {
    int b = blockIdx.x;
    const uint32_t* h = hist + b * HBUCK;
    __shared__ uint32_t p[256];
    __shared__ uint32_t sd;
    int t = threadIdx.x;
    if (t == 0) sd = 4096u;   // take-all sentinel (total < K)
    uint32_t loc[16];
    uint32_t s = 0;
    #pragma unroll
    for (int j = 0; j < 16; ++j) { loc[j] = h[t * 16 + j]; s += loc[j]; }
    p[t] = s;
    __syncthreads();
    for (int off = 1; off < 256; off <<= 1) {
        uint32_t add = (t >= off) ? p[t - off] : 0;
        __syncthreads();
        p[t] += add;
        __syncthreads();
    }
    uint32_t total = p[255];
    if (total >= K) {
        uint32_t run = p[t] - s;
        #pragma unroll
        for (int j = 0; j < 16; ++j) {
            uint32_t c = loc[j];
            if (run < K && run + c >= K) sd = (uint32_t)(t * 16 + j); // unique writer
            run += c;
        }
    }
    __syncthreads();
    if (t == 0) state[b * 8 + 2] = sd;
}

// ---------------- kernel 3: collect candidates + boundary (uint4) --------
__global__ __launch_bounds__(BLK) void k_collect(const uint32_t* __restrict__ keys,
                                                 uint32_t* __restrict__ state,
                                                 uint64_t* __restrict__ cand,
                                                 uint64_t* __restrict__ bound) {
    int b = blockIdx.x / BPB4;
    int base = (blockIdx.x % BPB4) * 1024 + threadIdx.x * 4;
    uint32_t d = state[b * 8 + 2];
    uint4 kv = make_uint4(0, 0, 0, 0);
    if (base < N) kv = *(const uint4*)(keys + (size_t)b * N + base);
    uint32_t ks[4] = { kv.x, kv.y, kv.z, kv.w };
    int lane = threadIdx.x & 63;

    #pragma unroll
    for (int e = 0; e < 4; ++e) {
        uint32_t key = ks[e];
        uint32_t bkt = key_bucket(key);
        bool isCand  = key && (bkt < d);
        bool isBound = key && (bkt == d);
        uint32_t i = (uint32_t)(base + e);
        uint64_t entry = ((uint64_t)key << 32) | (uint32_t)(~i);

        unsigned long long mc = __ballot(isCand);
        if (mc) {
            int leader = __ffsll((long long)mc) - 1;
            uint32_t basev = 0;
            if (lane == leader) basev = atomicAdd(&state[b * 8 + 4], (uint32_t)__popcll(mc));
            basev = __shfl(basev, leader);
            uint32_t pos = basev + (uint32_t)__popcll(mc & ((1ull << lane) - 1ull));
            if (isCand && pos < CAND_CAP) cand[(size_t)b * CAND_CAP + pos] = entry;
        }
        unsigned long long mb = __ballot(isBound);
        if (mb) {
            int leader = __ffsll((long long)mb) - 1;
            uint32_t basev = 0;
            if (lane == leader) basev = atomicAdd(&state[b * 8 + 5], (uint32_t)__popcll(mb));
            basev = __shfl(basev, leader);
            uint32_t pos = basev + (uint32_t)__popcll(mb & ((1ull << lane) - 1ull));
            if (isBound && pos < BOUND_CAP) bound[(size_t)b * BOUND_CAP + pos] = entry;
        }
    }
}

// ---------------- kernel 4: rank-by-counting + scatter outputs ----------
__global__ __launch_bounds__(256) void k_rank(const uint64_t* __restrict__ cand,
                                              const uint64_t* __restrict__ bound,
                                              const uint32_t* __restrict__ state,
                                              const uint8_t* __restrict__ labels,
                                              const float* __restrict__ boxes,
                                              float* __restrict__ out) {
    __shared__ uint64_t a[ENT_M];       // 32 KB
    int b = blockIdx.x / RANK_BLKS;
    int t0 = (blockIdx.x % RANK_BLKS) * 256;
    uint32_t cc = state[b * 8 + 4]; if (cc > CAND_CAP) cc = CAND_CAP;
    uint32_t bc = state[b * 8 + 5]; if (bc > BOUND_CAP) bc = BOUND_CAP;
    for (int i = threadIdx.x; i < ENT_M; i += 256) {
        uint64_t v = 0;
        if (i < (int)cc) v = cand[(size_t)b * CAND_CAP + i];
        else if (i < (int)(cc + bc)) v = bound[(size_t)b * BOUND_CAP + (i - cc)];
        a[i] = v;
    }
    __syncthreads();
    uint64_t e = a[t0 + threadIdx.x];
    if (e == 0) return;
    uint32_t rank = 0;
    #pragma unroll 8
    for (int j = 0; j < ENT_M; ++j) rank += (a[j] > e) ? 1u : 0u;  // LDS broadcast
    if (rank >= K) return;

    uint32_t sb  = (uint32_t)(e >> 32);
    uint32_t idx = ~((uint32_t)e);
    float* out_boxes  = out;                           // [B,K,6]
    float* out_scores = out + (size_t)B * K * 6;       // [B,K]
    float* out_labels = out_scores + (size_t)B * K;    // [B,K]
    out_scores[(size_t)b * K + rank] = __uint_as_float(sb);
    out_labels[(size_t)b * K + rank] = (float)labels[(size_t)b * N + idx];
    const float* bx = boxes + ((size_t)b * N + idx) * 6;
    float* ob = out_boxes + ((size_t)b * K + rank) * 6;
    #pragma unroll
    for (int c2 = 0; c2 < 6; ++c2) ob[c2] = bx[c2];
}

extern "C" void kernel_launch(void* const* d_in, const int* in_sizes, int n_in,
                              void* d_out, int out_size, void* d_ws, size_t ws_size,
                              hipStream_t stream) {
    const float* boxes = (const float*)d_in[0];          // [B,N,6]
    const float* cls   = (const float*)d_in[1];          // [B,N,C]
    float* out = (float*)d_out;

    char* ws = (char*)d_ws;
    uint32_t* keys    = (uint32_t*)ws;                             // B*N u32 (6.4 MB)
    uint8_t*  labels  = (uint8_t*)(ws + (size_t)B * N * 4);        // B*N u8  (1.6 MB)
    uint32_t* hist    = (uint32_t*)(ws + (size_t)B * N * 5);       // B*4096 u32
    uint32_t* state   = hist + (size_t)B * HBUCK;                  // B*8 u32
    uint64_t* cand    = (uint64_t*)(state + B * 8);
    uint64_t* bound   = cand + (size_t)B * CAND_CAP;
    uint32_t* keys2   = (uint32_t*)(bound + (size_t)B * BOUND_CAP); // scratch (probe)
    uint8_t*  labels2 = (uint8_t*)(keys2 + (size_t)B * N);          // scratch (probe)

    k_init<<<(B * K * 8 + 255) / 256, 256, 0, stream>>>(out, hist, state);
    // ATTRIBUTION PROBE: identical stream pass into scratch, then the real one.
    k_stream<<<B * NCHUNK, BLK, 0, stream>>>(cls, keys2, labels2);
    k_stream<<<B * NCHUNK, BLK, 0, stream>>>(cls, keys, labels);
    k_hist<<<B * BPB4, BLK, 0, stream>>>(keys, hist);
    k_scan<<<B, 256, 0, stream>>>(hist, state);
    k_collect<<<B * BPB4, BLK, 0, stream>>>(keys, state, cand, bound);
    k_rank<<<B * RANK_BLKS, 256, 0, stream>>>(cand, bound, state, labels, boxes, out);
}

// Round 9
// 228.713 us; speedup vs baseline: 1.5039x; 1.5039x over previous
//
#include <hip/hip_runtime.h>
#include <stdint.h>

#define B 8
#define N 200000
#define C 80
#define K 2000
#define HBUCK 4096
#define CAND_CAP 2048
#define BOUND_CAP 2048
#define ENT_M 4096              // CAND_CAP + BOUND_CAP
#define RANK_BLKS 16            // ENT_M / 256
#define BLK 256
#define CHUNK_ROWS 128
#define NCHUNK ((N + CHUNK_ROWS - 1) / CHUNK_ROWS)    // 1563 chunks per batch
#define F4_PER_ROW (C / 4)                            // 20
#define ROW_STRIDE 21                                 // coprime 32 -> conflict-free
#define F4_PER_THREAD (CHUNK_ROWS * F4_PER_ROW / BLK) // 10
#define BPB4 ((N + 1023) / 1024)                      // 196 blocks per batch (uint4)

// Bucket mapping: scores are float bits in (0, 1.0); off = 0x3F800000 - bits >= 1.
// bucket = min(4095, (off-1)>>8): buckets 0..4094 are 256-ulp slices of (0.9375, 1),
// bucket 4095 holds everything below. Descending score == ascending bucket.
__device__ __forceinline__ uint32_t key_bucket(uint32_t key) {
    uint32_t off = 0x3F800000u - key;
    uint32_t b = (off - 1u) >> 8;
    return b > 4095u ? 4095u : b;
}

// ---------------- kernel 1: PURE STREAM: score + argmax -> keys/labels ---
// 128-row chunks: LDS 15.75 KB, v[10] -> ~8 blocks/CU for max latency hiding.
// Blocks 0..127 also zero the global hist (written only by the NEXT kernel).
__global__ __launch_bounds__(BLK) void k_stream(const float* __restrict__ cls,
                                                uint32_t* __restrict__ keys,
                                                uint8_t* __restrict__ labels,
                                                uint32_t* __restrict__ hist) {
    __shared__ float    sval[CHUNK_ROWS * ROW_STRIDE];      // 10.5 KB
    __shared__ uint16_t sidx[CHUNK_ROWS * ROW_STRIDE];      // 5.25 KB
    if (blockIdx.x < 128) {   // B*HBUCK = 128*1024
        uint32_t* hz = hist + (size_t)blockIdx.x * 1024;
        #pragma unroll
        for (int t = 0; t < 1024 / BLK; ++t) hz[threadIdx.x + t * BLK] = 0;
    }
    int b = blockIdx.x / NCHUNK;
    int row0 = (blockIdx.x % NCHUNK) * CHUNK_ROWS;
    const float4* src = (const float4*)(cls + ((size_t)b * N + row0) * C);

    if (row0 + CHUNK_ROWS <= N) {
        float4 v[F4_PER_THREAD];
        #pragma unroll
        for (int kk = 0; kk < F4_PER_THREAD; ++kk)
            v[kk] = src[threadIdx.x + kk * BLK];
        #pragma unroll
        for (int kk = 0; kk < F4_PER_THREAD; ++kk) {
            int f = threadIdx.x + kk * BLK;
            int r = f / F4_PER_ROW;
            int cc = f % F4_PER_ROW;
            float m4 = v[kk].x; uint32_t a4 = 0;
            if (v[kk].y > m4) { m4 = v[kk].y; a4 = 1; }
            if (v[kk].z > m4) { m4 = v[kk].z; a4 = 2; }
            if (v[kk].w > m4) { m4 = v[kk].w; a4 = 3; }
            sval[r * ROW_STRIDE + cc] = m4;
            sidx[r * ROW_STRIDE + cc] = (uint16_t)(cc * 4 + a4);
        }
    } else {
        #pragma unroll
        for (int kk = 0; kk < F4_PER_THREAD; ++kk) {
            int f = threadIdx.x + kk * BLK;
            int r = f / F4_PER_ROW;
            int cc = f % F4_PER_ROW;
            float m4 = -1.0f; uint32_t a4 = 0;
            if (row0 + r < N) {
                float4 v = src[f];
                m4 = v.x; a4 = 0;
                if (v.y > m4) { m4 = v.y; a4 = 1; }
                if (v.z > m4) { m4 = v.z; a4 = 2; }
                if (v.w > m4) { m4 = v.w; a4 = 3; }
            }
            sval[r * ROW_STRIDE + cc] = m4;
            sidx[r * ROW_STRIDE + cc] = (uint16_t)(cc * 4 + a4);
        }
    }
    __syncthreads();

    int grow = row0 + threadIdx.x;
    if (threadIdx.x < CHUNK_ROWS && grow < N) {
        int base = threadIdx.x * ROW_STRIDE;
        float maxv = -1.0f; uint32_t maxi = 0;
        #pragma unroll
        for (int cc = 0; cc < F4_PER_ROW; ++cc) {
            float v = sval[base + cc];
            if (v > maxv) { maxv = v; maxi = sidx[base + cc]; }
        }
        uint32_t key = (maxv > 0.05f) ? __float_as_uint(maxv) : 0u;
        keys[(size_t)b * N + grow] = key;
        labels[(size_t)b * N + grow] = (uint8_t)maxi;
    }
}

// ---------------- kernel 1b: hist from keys (LDS + spread global flush) --
__global__ __launch_bounds__(BLK) void k_hist(const uint32_t* __restrict__ keys,
                                              uint32_t* __restrict__ hist) {
    __shared__ uint32_t h[HBUCK];
    for (int t = threadIdx.x; t < HBUCK; t += BLK) h[t] = 0;
    __syncthreads();
    int b = blockIdx.x / BPB4;
    int base = (blockIdx.x % BPB4) * 1024 + threadIdx.x * 4;
    if (base < N) {
        uint4 kv = *(const uint4*)(keys + (size_t)b * N + base);
        if (kv.x) atomicAdd(&h[key_bucket(kv.x)], 1u);
        if (kv.y) atomicAdd(&h[key_bucket(kv.y)], 1u);
        if (kv.z) atomicAdd(&h[key_bucket(kv.z)], 1u);
        if (kv.w) atomicAdd(&h[key_bucket(kv.w)], 1u);
    }
    __syncthreads();
    for (int t = threadIdx.x; t < HBUCK; t += BLK) {
        uint32_t c = h[t];
        if (c) atomicAdd(&hist[b * HBUCK + t], c);
    }
}

// ---------------- kernel 2: scan -> cutoff; also zero state, fill out=-1 -
__global__ __launch_bounds__(256) void k_scan(const uint32_t* __restrict__ hist,
                                              uint32_t* __restrict__ state,
                                              float* __restrict__ out) {
    int b = blockIdx.x;
    const uint32_t* h = hist + b * HBUCK;
    __shared__ uint32_t p[256];
    __shared__ uint32_t sd;
    int t = threadIdx.x;
    if (t == 0) sd = 4096u;   // take-all sentinel (total < K)
    uint32_t loc[16];
    uint32_t s = 0;
    #pragma unroll
    for (int j = 0; j < 16; ++j) { loc[j] = h[t * 16 + j]; s += loc[j]; }
    p[t] = s;
    __syncthreads();
    for (int off = 1; off < 256; off <<= 1) {
        uint32_t add = (t >= off) ? p[t - off] : 0;
        __syncthreads();
        p[t] += add;
        __syncthreads();
    }
    uint32_t total = p[255];
    if (total >= K) {
        uint32_t run = p[t] - s;
        #pragma unroll
        for (int j = 0; j < 16; ++j) {
            uint32_t c = loc[j];
            if (run < K && run + c >= K) sd = (uint32_t)(t * 16 + j); // unique writer
            run += c;
        }
    }
    __syncthreads();
    if (t == 0) { state[b * 8 + 2] = sd; state[b * 8 + 4] = 0; state[b * 8 + 5] = 0; }
    // fill this batch's output slices with -1 (runs before collect/rank)
    float* ob = out + (size_t)b * K * 6;                       // boxes [K,6]
    for (int i = t; i < K * 6; i += 256) ob[i] = -1.0f;
    float* os = out + (size_t)B * K * 6 + (size_t)b * K;       // scores [K]
    float* ol = out + (size_t)B * K * 6 + (size_t)B * K + (size_t)b * K; // labels [K]
    for (int i = t; i < K; i += 256) { os[i] = -1.0f; ol[i] = -1.0f; }
}

// ---------------- kernel 3: collect candidates + boundary (uint4) --------
__global__ __launch_bounds__(BLK) void k_collect(const uint32_t* __restrict__ keys,
                                                 uint32_t* __restrict__ state,
                                                 uint64_t* __restrict__ cand,
                                                 uint64_t* __restrict__ bound) {
    int b = blockIdx.x / BPB4;
    int base = (blockIdx.x % BPB4) * 1024 + threadIdx.x * 4;
    uint32_t d = state[b * 8 + 2];
    uint4 kv = make_uint4(0, 0, 0, 0);
    if (base < N) kv = *(const uint4*)(keys + (size_t)b * N + base);
    uint32_t ks[4] = { kv.x, kv.y, kv.z, kv.w };
    int lane = threadIdx.x & 63;

    #pragma unroll
    for (int e = 0; e < 4; ++e) {
        uint32_t key = ks[e];
        uint32_t bkt = key_bucket(key);
        bool isCand  = key && (bkt < d);
        bool isBound = key && (bkt == d);
        uint32_t i = (uint32_t)(base + e);
        uint64_t entry = ((uint64_t)key << 32) | (uint32_t)(~i);

        unsigned long long mc = __ballot(isCand);
        if (mc) {
            int leader = __ffsll((long long)mc) - 1;
            uint32_t basev = 0;
            if (lane == leader) basev = atomicAdd(&state[b * 8 + 4], (uint32_t)__popcll(mc));
            basev = __shfl(basev, leader);
            uint32_t pos = basev + (uint32_t)__popcll(mc & ((1ull << lane) - 1ull));
            if (isCand && pos < CAND_CAP) cand[(size_t)b * CAND_CAP + pos] = entry;
        }
        unsigned long long mb = __ballot(isBound);
        if (mb) {
            int leader = __ffsll((long long)mb) - 1;
            uint32_t basev = 0;
            if (lane == leader) basev = atomicAdd(&state[b * 8 + 5], (uint32_t)__popcll(mb));
            basev = __shfl(basev, leader);
            uint32_t pos = basev + (uint32_t)__popcll(mb & ((1ull << lane) - 1ull));
            if (isBound && pos < BOUND_CAP) bound[(size_t)b * BOUND_CAP + pos] = entry;
        }
    }
}

// ---------------- kernel 4: rank-by-counting + scatter outputs ----------
// Loop bound is the ACTUAL entry count n (~2100), not the fixed capacity.
__global__ __launch_bounds__(256) void k_rank(const uint64_t* __restrict__ cand,
                                              const uint64_t* __restrict__ bound,
                                              const uint32_t* __restrict__ state,
                                              const uint8_t* __restrict__ labels,
                                              const float* __restrict__ boxes,
                                              float* __restrict__ out) {
    __shared__ uint64_t a[ENT_M];       // 32 KB
    int b = blockIdx.x / RANK_BLKS;
    int t0 = (blockIdx.x % RANK_BLKS) * 256;
    uint32_t cc = state[b * 8 + 4]; if (cc > CAND_CAP) cc = CAND_CAP;
    uint32_t bc = state[b * 8 + 5]; if (bc > BOUND_CAP) bc = BOUND_CAP;
    int n = (int)(cc + bc);
    if (t0 >= n) return;                 // whole block beyond live entries
    for (int i = threadIdx.x; i < n; i += 256) {
        a[i] = (i < (int)cc) ? cand[(size_t)b * CAND_CAP + i]
                             : bound[(size_t)b * BOUND_CAP + (i - cc)];
    }
    __syncthreads();
    int me = t0 + threadIdx.x;
    if (me >= n) return;
    uint64_t e = a[me];
    if (e == 0) return;
    uint32_t rank = 0;
    #pragma unroll 8
    for (int j = 0; j < n; ++j) rank += (a[j] > e) ? 1u : 0u;   // LDS broadcast
    if (rank >= K) return;

    uint32_t sb  = (uint32_t)(e >> 32);
    uint32_t idx = ~((uint32_t)e);
    float* out_boxes  = out;                           // [B,K,6]
    float* out_scores = out + (size_t)B * K * 6;       // [B,K]
    float* out_labels = out_scores + (size_t)B * K;    // [B,K]
    out_scores[(size_t)b * K + rank] = __uint_as_float(sb);
    out_labels[(size_t)b * K + rank] = (float)labels[(size_t)b * N + idx];
    const float* bx = boxes + ((size_t)b * N + idx) * 6;
    float* ob = out_boxes + ((size_t)b * K + rank) * 6;
    #pragma unroll
    for (int c2 = 0; c2 < 6; ++c2) ob[c2] = bx[c2];
}

extern "C" void kernel_launch(void* const* d_in, const int* in_sizes, int n_in,
                              void* d_out, int out_size, void* d_ws, size_t ws_size,
                              hipStream_t stream) {
    const float* boxes = (const float*)d_in[0];          // [B,N,6]
    const float* cls   = (const float*)d_in[1];          // [B,N,C]
    float* out = (float*)d_out;

    char* ws = (char*)d_ws;
    uint32_t* keys    = (uint32_t*)ws;                             // B*N u32 (6.4 MB)
    uint8_t*  labels  = (uint8_t*)(ws + (size_t)B * N * 4);        // B*N u8  (1.6 MB)
    uint32_t* hist    = (uint32_t*)(ws + (size_t)B * N * 5);       // B*4096 u32
    uint32_t* state   = hist + (size_t)B * HBUCK;                  // B*8 u32
    uint64_t* cand    = (uint64_t*)(state + B * 8);
    uint64_t* bound   = cand + (size_t)B * CAND_CAP;

    k_stream<<<B * NCHUNK, BLK, 0, stream>>>(cls, keys, labels, hist);
    k_hist<<<B * BPB4, BLK, 0, stream>>>(keys, hist);
    k_scan<<<B, 256, 0, stream>>>(hist, state, out);
    k_collect<<<B * BPB4, BLK, 0, stream>>>(keys, state, cand, bound);
    k_rank<<<B * RANK_BLKS, 256, 0, stream>>>(cand, bound, state, labels, boxes, out);
}